// Round 12
// baseline (143.896 us; speedup 1.0000x reference)
//
#include <hip/hip_runtime.h>
#include <hip/hip_bf16.h>
#include <stdint.h>

typedef unsigned short u16;
typedef uint32_t u32;
typedef unsigned long long u64;
typedef __attribute__((ext_vector_type(8))) short bf16x8;
typedef __attribute__((ext_vector_type(4))) float f32x4;
typedef __attribute__((ext_vector_type(16))) float f32x16;
typedef __attribute__((ext_vector_type(2))) unsigned int u32x2;
typedef __attribute__((ext_vector_type(4))) u32 u32x4;

#define T_SEQ 2048

__device__ __forceinline__ float bf2f(u16 u) {
  union { u32 i; float f; } v; v.i = ((u32)u) << 16; return v.f;
}
__device__ __forceinline__ u16 f2bf(float f) {
  union { float f; u32 i; } v; v.f = f;
  u32 u = v.i;
  return (u16)((u + 0x7fffu + ((u >> 16) & 1u)) >> 16);
}

#if __has_builtin(__builtin_amdgcn_exp2f)
#define EXP2F(x) __builtin_amdgcn_exp2f(x)
#else
#define EXP2F(x) exp2f(x)
#endif

__device__ __forceinline__ u32 permpack(float lo, float hi) {
#if __has_builtin(__builtin_amdgcn_perm)
  return __builtin_amdgcn_perm(__float_as_uint(hi), __float_as_uint(lo), 0x07060302u);
#else
  return (__float_as_uint(hi) & 0xFFFF0000u) | (__float_as_uint(lo) >> 16);
#endif
}

__device__ __forceinline__ void plswap(u32& a, u32& b) {
#if __has_builtin(__builtin_amdgcn_permlane32_swap)
  u32x2 r = __builtin_amdgcn_permlane32_swap(a, b, false, false);
  a = r[0]; b = r[1];
#else
  u32 ra = __shfl_xor(a, 32, 64), rb = __shfl_xor(b, 32, 64);
  const bool hi_ = (threadIdx.x & 32) != 0;
  u32 na = hi_ ? rb : a;
  u32 nb = hi_ ? b : ra;
  a = na; b = nb;
#endif
}
__device__ __forceinline__ float othhalf(float x, bool ishi) {
  u32 a = __float_as_uint(x), b = a;
  plswap(a, b);
  return __uint_as_float(ishi ? a : b);
}

__device__ __forceinline__ void gload_lds16(const void* g, void* l) {
  __builtin_amdgcn_global_load_lds(
      (const __attribute__((address_space(1))) void*)g,
      (__attribute__((address_space(3))) void*)l, 16, 0, 0);
}

// ---- fp32 -> bf16 convert (query + 4 weights) + kpm bit-pack, one dispatch --
__global__ __launch_bounds__(256) void cvt5_kernel(
    const float* __restrict__ qsrc, const float* __restrict__ w0,
    const float* __restrict__ w1, const float* __restrict__ w2,
    const float* __restrict__ w3, const int* __restrict__ kpm,
    u16* __restrict__ qbf, u16* __restrict__ wbf, u64* __restrict__ kpmbits) {
  const int bx = blockIdx.x;
  if (bx == 8192) {
    // pack kpm[2][2048] -> kpmbits[64] (one u64 per (b, 64-kv tile))
    const int wv = threadIdx.x >> 6, lane = threadIdx.x & 63;
    for (int pair = wv; pair < 64; pair += 4) {
      int v = kpm[pair*64 + lane];
      u64 m = __ballot(v != 0);
      if (lane == 0) kpmbits[pair] = m;
    }
    return;
  }
  const float* src; u16* dst; int i;
  if (bx < 4096) {
    src = qsrc; dst = qbf; i = (bx*256 + threadIdx.x)*4;
  } else {
    int t = bx - 4096;
    int z = t >> 10;
    src = (z == 0) ? w0 : (z == 1) ? w1 : (z == 2) ? w2 : w3;
    dst = wbf + (size_t)z * 1048576;
    i = ((t & 1023)*256 + threadIdx.x)*4;
  }
  const float4 v = *(const float4*)(src + i);
  ushort4 o;
  o.x = f2bf(v.x); o.y = f2bf(v.y); o.z = f2bf(v.z); o.w = f2bf(v.w);
  *(ushort4*)(dst + i) = o;
}

// ------- GEMM core: C[128x128] += A[128xK] * B[128xK]^T, K=1024, 8 waves ---
__device__ __forceinline__ void gemm_core_128x128(
    f32x4 acc[2][4], const u16* __restrict__ A, const u16* __restrict__ Bw,
    int bm, int bn, u16* As, u16* Bs)
{
  const int tid = threadIdx.x;
  const int w = tid >> 6, lane = tid & 63, g = lane >> 4, c = lane & 15;
  const int wr = (w & 3) * 32, wc = (w >> 2) * 64;
  for (int k0 = 0; k0 < 1024; k0 += 64) {
    __syncthreads();
    #pragma unroll
    for (int is = 0; is < 2; ++is) {
      int o = (is*8 + w)*1024 + lane*16;
      int row = o >> 7, c16 = (o >> 4) & 7;
      gload_lds16(A + (size_t)(bm*128 + row)*1024 + k0 + (c16 ^ (row & 7))*8,
                  (char*)As + (is*8 + w)*1024);
    }
    #pragma unroll
    for (int is = 0; is < 2; ++is) {
      int o = (is*8 + w)*1024 + lane*16;
      int row = o >> 7, c16 = (o >> 4) & 7;
      gload_lds16(Bw + (size_t)(bn*128 + row)*1024 + k0 + (c16 ^ (row & 7))*8,
                  (char*)Bs + (is*8 + w)*1024);
    }
    __syncthreads();
    bf16x8 af[2][2], bfr[4][2];
    #pragma unroll
    for (int mf = 0; mf < 2; ++mf)
      #pragma unroll
      for (int kc = 0; kc < 2; ++kc) {
        int row = wr + mf*16 + c;
        int colb = kc*64 + g*16;
        af[mf][kc] = *(const bf16x8*)((const char*)As + row*128 + (colb ^ ((row & 7) << 4)));
      }
    #pragma unroll
    for (int nf = 0; nf < 4; ++nf)
      #pragma unroll
      for (int kc = 0; kc < 2; ++kc) {
        int row = wc + nf*16 + c;
        int colb = kc*64 + g*16;
        bfr[nf][kc] = *(const bf16x8*)((const char*)Bs + row*128 + (colb ^ ((row & 7) << 4)));
      }
    #pragma unroll
    for (int mf = 0; mf < 2; ++mf)
      #pragma unroll
      for (int nf = 0; nf < 4; ++nf)
        #pragma unroll
        for (int kc = 0; kc < 2; ++kc)
          acc[mf][nf] = __builtin_amdgcn_mfma_f32_16x16x32_bf16(
              af[mf][kc], bfr[nf][kc], acc[mf][nf], 0, 0, 0);
  }
}

// ---------------- QKV projection: ONE dispatch over concat [3072][1024] ----
__global__ __launch_bounds__(512, 2) void gemm_qkv(
    const u16* __restrict__ Abf, const u16* __restrict__ Wbf,
    const float* __restrict__ bq, const float* __restrict__ bk,
    const float* __restrict__ bv, u16* __restrict__ qkvh)
{
  __shared__ __align__(16) u16 As[128*64];
  __shared__ __align__(16) u16 Bs[128*64];
  f32x4 acc[2][4];
  #pragma unroll
  for (int mf = 0; mf < 2; ++mf)
    #pragma unroll
    for (int nf = 0; nf < 4; ++nf) acc[mf][nf] = (f32x4){0.f,0.f,0.f,0.f};
  const int bx = blockIdx.x;
  const int bm = (bx & 7) * 4 + (bx >> 3);
  gemm_core_128x128(acc, Abf, Wbf, bm, blockIdx.y, As, Bs);
  const int tid = threadIdx.x, w = tid >> 6, lane = tid & 63, g = lane >> 4, c = lane & 15;
  const int wr = (w & 3) * 32, wc = (w >> 2) * 64;
  #pragma unroll
  for (int mf = 0; mf < 2; ++mf)
    #pragma unroll
    for (int nf = 0; nf < 4; ++nf) {
      int col = blockIdx.y*128 + wc + nf*16 + c;      // 0..3071
      int z = col >> 10, colz = col & 1023;
      const float* bias = (z == 0) ? bq : (z == 1) ? bk : bv;
      float bcol = bias[colz];
      float scl = (z == 0) ? 0.18033688011112043f : 1.0f;  // 0.125 * log2(e)
      int h = colz >> 6, d = colz & 63;
      u16* dst = qkvh + (size_t)z * 4194304;
      #pragma unroll
      for (int r = 0; r < 4; ++r) {
        int row = bm*128 + wr + mf*16 + g*4 + r;
        int t = row >> 1, bb = row & 1;
        float v = (acc[mf][nf][r] + bcol) * scl;
        dst[(size_t)(bb*16 + h)*131072 + (size_t)t*64 + d] = f2bf(v);
      }
    }
}

// ---------------- output projection (128x128 tile, 512 thr) ----------------
__global__ __launch_bounds__(512, 2) void gemm_out(
    const u16* __restrict__ ctx2, const u16* __restrict__ Wobf,
    const float* __restrict__ bo, float* __restrict__ out)
{
  __shared__ __align__(16) u16 As[128*64];
  __shared__ __align__(16) u16 Bs[128*64];
  f32x4 acc[2][4];
  #pragma unroll
  for (int mf = 0; mf < 2; ++mf)
    #pragma unroll
    for (int nf = 0; nf < 4; ++nf) acc[mf][nf] = (f32x4){0.f,0.f,0.f,0.f};
  const int bx = blockIdx.x;
  const int bm = (bx & 7) * 4 + (bx >> 3);
  gemm_core_128x128(acc, ctx2, Wobf, bm, blockIdx.y, As, Bs);
  const int tid = threadIdx.x, w = tid >> 6, lane = tid & 63, g = lane >> 4, c = lane & 15;
  const int wr = (w & 3) * 32, wc = (w >> 2) * 64;
  #pragma unroll
  for (int mf = 0; mf < 2; ++mf)
    #pragma unroll
    for (int nf = 0; nf < 4; ++nf) {
      int col = blockIdx.y*128 + wc + nf*16 + c;
      float bcol = bo[col];
      #pragma unroll
      for (int r = 0; r < 4; ++r) {
        int row = bm*128 + wr + mf*16 + g*4 + r;
        out[(size_t)row*1024 + col] = acc[mf][nf][r] + bcol;
      }
    }
}

// ---------------- V transpose + column sums ----------------
__global__ __launch_bounds__(256) void vtrans_kernel(const u16* __restrict__ Vh,
                                                     u16* __restrict__ Vt,
                                                     float* __restrict__ vs) {
  __shared__ u16 tile[64][72];
  const int bh = blockIdx.x >> 5, tc = blockIdx.x & 31;
  const int t0 = tc * 64;
  const int tid = threadIdx.x;
  {
    const int tl = tid >> 2, d0 = (tid & 3) * 16;
    const u16* src = Vh + (size_t)bh*131072 + (size_t)(t0 + tl)*64 + d0;
    bf16x8 a = *(const bf16x8*)src;
    bf16x8 b2 = *(const bf16x8*)(src + 8);
    #pragma unroll
    for (int j = 0; j < 8; ++j) {
      tile[d0 + j][tl] = (u16)a[j];
      tile[d0 + 8 + j][tl] = (u16)b2[j];
    }
  }
  __syncthreads();
  {
    const int d = tid >> 2, tq = (tid & 3) * 16;
    bf16x8 o0, o1;
    float s = 0.f;
    #pragma unroll
    for (int j = 0; j < 8; ++j) {
      u16 x0 = tile[d][tq + j], x1 = tile[d][tq + 8 + j];
      o0[j] = (short)x0; o1[j] = (short)x1;
      s += bf2f(x0) + bf2f(x1);
    }
    u16* dst = Vt + (size_t)bh*131072 + (size_t)d*2048 + t0 + tq;
    *(bf16x8*)dst = o0;
    *(bf16x8*)(dst + 8) = o1;
    s += __shfl_xor(s, 1, 64);
    s += __shfl_xor(s, 2, 64);
    if ((tid & 3) == 0) atomicAdd(&vs[bh*64 + d], s);
  }
}

// ---------------- flash attention: counted-vmcnt pipeline (T4) -------------
// grid 1280 = 8 XCD x 4 bh x 40 chunks (CTBL quintets, all chunks <=8 iters).
// 2-deep staging: prologue stages tiles lo,lo+1; per iter wait vmcnt(4)
// (NEVER 0 mid-loop -> next tile's loads stay in flight across barriers),
// raw s_barrier, compute, raw s_barrier, stage t+2. Per-wave op count fixed
// (4 gload_lds/tile/wave) so each wave's own vmcnt certifies tile done.
// kpm consumed as precomputed bitmasks (no per-iter ballot/load in vmcnt path).
#define ZERO16 (f32x16){0.f,0.f,0.f,0.f,0.f,0.f,0.f,0.f,0.f,0.f,0.f,0.f,0.f,0.f,0.f,0.f}
#define NEGINF (-__builtin_inff())

__device__ const unsigned char CTBL[40] = {
  60, 44, 28, 12, 57, 59, 52, 37,
  61, 45, 29, 42, 40, 56, 53, 38,
  62, 46, 24, 25, 41, 58, 54, 49,
  63,  8, 20, 21, 32, 34, 55, 51,
   0,  4, 16, 17, 33, 36, 48, 50 };

__device__ __forceinline__ int pctx_off(int k, int ch) {
  if (k < 8)  return (k - 4);
  if (k < 12) return 4 + (k - 8)*2 + (ch - 1);
  return 12 + (k - 12)*3 + (ch - 1);
}
__device__ __forceinline__ int pml_off(int k, int ch) {
  if (k < 8)  return (k - 4)*2 + ch;
  if (k < 12) return 8 + (k - 8)*3 + ch;
  return 20 + (k - 12)*4 + ch;
}

__global__ __launch_bounds__(256, 2) void flash_attn(
    const u16* __restrict__ Qh, const u16* __restrict__ Kh,
    const u16* __restrict__ Vt, const u64* __restrict__ kpmbits,
    const float* __restrict__ vsum, u16* __restrict__ ctx2,
    u16* __restrict__ pctxA, u16* __restrict__ pctxB,
    float* __restrict__ pml)
{
  __shared__ __align__(16) u16 Kl[2][4096];
  __shared__ __align__(16) u16 Vl[2][4096];

  const int tid = threadIdx.x;
  const int w = tid >> 6, lane = tid & 63;
  const int l31 = lane & 31, hi = lane >> 5;

  const int id = blockIdx.x;
  const int xcd = id & 7, rest = id >> 3;
  const int bh = xcd * 4 + (rest & 3);
  const int cidx = rest >> 2;            // 0..39
  const int v_tbl = CTBL[cidx];
  const int k = v_tbl >> 2, ch = v_tbl & 3;
  const int NS = (k >> 2) + 1;
  const int nt = 2*k + 2;
  const int lo = (nt * ch) / NS, hicap = (nt * (ch + 1)) / NS;

  const int b = bh >> 4, h = bh & 15;
  const size_t hbase = (size_t)bh * 131072;
  const int q = 128*k + 32*w + l31;
  const int myNt = 2*k + 1 + (w >> 1);

  bf16x8 qfrag[4];
  #pragma unroll
  for (int kt = 0; kt < 4; ++kt)
    qfrag[kt] = *(const bf16x8*)(Qh + hbase + (size_t)q*64 + kt*16 + hi*8);

  // staging helper pattern (4 gload_lds per wave per tile)
  const int jb = (w & 1) * 4;

  // prologue: load mask(lo); stage tiles lo and lo+1
  u64 mcur = kpmbits[(b << 5) + lo];
  {
    const int s0t = lo * 64;
    if (w < 2) {
      #pragma unroll
      for (int is = 0; is < 4; ++is) {
        int o = (jb + is)*1024 + lane*16;
        int row = o >> 7, c16 = (o >> 4) & 7;
        gload_lds16(Kh + hbase + (size_t)(s0t + row)*64 + (c16 ^ (row & 7))*8,
                    (char*)Kl[0] + (jb + is)*1024);
      }
    } else {
      #pragma unroll
      for (int is = 0; is < 4; ++is) {
        int o = (jb + is)*1024 + lane*16;
        int row = o >> 7, c16 = (o >> 4) & 7;
        gload_lds16(Vt + hbase + (size_t)row*2048 + s0t + (c16 ^ (row & 7))*8,
                    (char*)Vl[0] + (jb + is)*1024);
      }
    }
  }
  if (lo + 1 < hicap) {
    const int s0t = (lo + 1) * 64;
    if (w < 2) {
      #pragma unroll
      for (int is = 0; is < 4; ++is) {
        int o = (jb + is)*1024 + lane*16;
        int row = o >> 7, c16 = (o >> 4) & 7;
        gload_lds16(Kh + hbase + (size_t)(s0t + row)*64 + (c16 ^ (row & 7))*8,
                    (char*)Kl[1] + (jb + is)*1024);
      }
    } else {
      #pragma unroll
      for (int is = 0; is < 4; ++is) {
        int o = (jb + is)*1024 + lane*16;
        int row = o >> 7, c16 = (o >> 4) & 7;
        gload_lds16(Vt + hbase + (size_t)row*2048 + s0t + (c16 ^ (row & 7))*8,
                    (char*)Vl[1] + (jb + is)*1024);
      }
    }
  }

  float mrow = NEGINF, lrow = 0.f;
  f32x16 cacc0 = ZERO16, cacc1 = ZERO16;

  for (int t = lo; t < hicap; ++t) {
    const int cur = (t - lo) & 1;
    const int s0 = t * 64;
    const bool haveNext = (t + 1 < hicap);
    const bool diag = (t >= myNt - 1);

    // counted wait: tile t's loads (oldest) complete; t+1's stay in flight
    if (haveNext) asm volatile("s_waitcnt vmcnt(4)" ::: "memory");
    else          asm volatile("s_waitcnt vmcnt(0)" ::: "memory");
    u64 mnxt = haveNext ? kpmbits[(b << 5) + t + 1] : 0;
    __builtin_amdgcn_s_barrier();

    // kill bitmasks from mcur (VALU only)
    u32 kill0 = 0, kill1 = 0;
    {
      const u32 m0 = (u32)mcur, m1 = (u32)(mcur >> 32);
      const u64 m4 = mcur >> 4;
      const u32 m4l = (u32)m4, m4h = (u32)(m4 >> 32);
      const u32 w0m = hi ? m4l : m0;
      const u32 w1m = hi ? m4h : m1;
      const int lim = q - s0 - 4*hi;
      #pragma unroll
      for (int m = 0; m < 4; ++m) {
        u32 nib0 = (w0m >> (m*8)) & 15u;
        u32 nib1 = (w1m >> (m*8)) & 15u;
        if (diag) {
          int t0c = lim - m*8;       int c0 = min(max(t0c + 1, 0), 4);
          int t1c = lim - 32 - m*8;  int c1 = min(max(t1c + 1, 0), 4);
          nib0 |= (0xFu << c0) & 0xFu;
          nib1 |= (0xFu << c1) & 0xFu;
        }
        kill0 |= nib0 << (m*4);
        kill1 |= nib1 << (m*4);
      }
    }
    f32x16 st0, st1;
    #pragma unroll
    for (int i = 0; i < 16; ++i) {
      st0[i] = ((kill0 >> i) & 1u) ? NEGINF : 0.f;
      st1[i] = ((kill1 >> i) & 1u) ? NEGINF : 0.f;
    }

    bf16x8 kreg[2][4], vf[2][4];
    #pragma unroll
    for (int sub = 0; sub < 2; ++sub)
      #pragma unroll
      for (int kt = 0; kt < 4; ++kt) {
        int row = sub*32 + l31;
        int colb = kt*32 + hi*16;
        kreg[sub][kt] = *(const bf16x8*)((const char*)Kl[cur] + row*128 + (colb ^ ((row & 7) << 4)));
        vf[sub][kt]   = *(const bf16x8*)((const char*)Vl[cur] + row*128 + (colb ^ ((row & 7) << 4)));
      }

    __builtin_amdgcn_s_setprio(1);
    #pragma unroll
    for (int kt = 0; kt < 4; ++kt) {
      st0 = __builtin_amdgcn_mfma_f32_32x32x16_bf16(kreg[0][kt], qfrag[kt], st0, 0, 0, 0);
      st1 = __builtin_amdgcn_mfma_f32_32x32x16_bf16(kreg[1][kt], qfrag[kt], st1, 0, 0, 0);
    }
    __builtin_amdgcn_s_setprio(0);

    // online softmax (per-lane, exp2 domain, defer-rescale)
    {
      float t8[8];
      #pragma unroll
      for (int i = 0; i < 8; ++i)
        t8[i] = fmaxf(fmaxf(st0[i], st0[i+8]), fmaxf(st1[i], st1[i+8]));
      float t4a = fmaxf(t8[0], t8[4]), t4b = fmaxf(t8[1], t8[5]);
      float t4c = fmaxf(t8[2], t8[6]), t4d = fmaxf(t8[3], t8[7]);
      float rm = fmaxf(fmaxf(t4a, t4b), fmaxf(t4c, t4d));
      rm = fmaxf(rm, othhalf(rm, hi != 0));

      const bool need = (rm > mrow + 8.f) || (mrow < -1e30f);
      if (__any(need)) {
        const float mn = fmaxf(mrow, rm);
        const float sc = (mn < -1e30f) ? 1.f : EXP2F(mrow - mn);
        mrow = mn;
        lrow *= sc;
        #pragma unroll
        for (int i = 0; i < 16; ++i) { cacc0[i] *= sc; cacc1[i] *= sc; }
      }
      const bool dead = (mrow < -1e30f);
      float a0 = 0.f, a1 = 0.f, a2 = 0.f, a3 = 0.f;
      #pragma unroll
      for (int i = 0; i < 16; i += 4) {
        float p0 = dead ? 0.f : EXP2F(st0[i+0] - mrow); st0[i+0] = p0; a0 += p0;
        float p1 = dead ? 0.f : EXP2F(st0[i+1] - mrow); st0[i+1] = p1; a1 += p1;
        float p2 = dead ? 0.f : EXP2F(st0[i+2] - mrow); st0[i+2] = p2; a2 += p2;
        float p3 = dead ? 0.f : EXP2F(st0[i+3] - mrow); st0[i+3] = p3; a3 += p3;
      }
      #pragma unroll
      for (int i = 0; i < 16; i += 4) {
        float p0 = dead ? 0.f : EXP2F(st1[i+0] - mrow); st1[i+0] = p0; a0 += p0;
        float p1 = dead ? 0.f : EXP2F(st1[i+1] - mrow); st1[i+1] = p1; a1 += p1;
        float p2 = dead ? 0.f : EXP2F(st1[i+2] - mrow); st1[i+2] = p2; a2 += p2;
        float p3 = dead ? 0.f : EXP2F(st1[i+3] - mrow); st1[i+3] = p3; a3 += p3;
      }
      float ps = (a0 + a1) + (a2 + a3);
      ps += othhalf(ps, hi != 0);
      lrow += ps;
    }

    // pack P to bf16 pairs
    u32 pk[8][2];
    #pragma unroll
    for (int m = 0; m < 4; ++m) {
      pk[m][0]   = permpack(st0[m*4+0], st0[m*4+1]);
      pk[m][1]   = permpack(st0[m*4+2], st0[m*4+3]);
      pk[4+m][0] = permpack(st1[m*4+0], st1[m*4+1]);
      pk[4+m][1] = permpack(st1[m*4+2], st1[m*4+3]);
    }
    bf16x8 pf[4];
    #pragma unroll
    for (int ks = 0; ks < 4; ++ks) {
      u32 w0p = pk[2*ks][0], w2p = pk[2*ks+1][0];
      u32 w1p = pk[2*ks][1], w3p = pk[2*ks+1][1];
      plswap(w0p, w2p);
      plswap(w1p, w3p);
      u32x4 wv = {w0p, w1p, w2p, w3p};
      pf[ks] = __builtin_bit_cast(bf16x8, wv);
    }

    __builtin_amdgcn_s_setprio(1);
    #pragma unroll
    for (int ks = 0; ks < 4; ++ks)
      cacc0 = __builtin_amdgcn_mfma_f32_32x32x16_bf16(vf[0][ks], pf[ks], cacc0, 0, 0, 0);
    #pragma unroll
    for (int ks = 0; ks < 4; ++ks)
      cacc1 = __builtin_amdgcn_mfma_f32_32x32x16_bf16(vf[1][ks], pf[ks], cacc1, 0, 0, 0);
    __builtin_amdgcn_s_setprio(0);

    // all waves done reading buf[cur]; re-stage it with tile t+2
    __builtin_amdgcn_s_barrier();
    if (t + 2 < hicap) {
      const int s0n = (t + 2) * 64;
      if (w < 2) {
        #pragma unroll
        for (int is = 0; is < 4; ++is) {
          int o = (jb + is)*1024 + lane*16;
          int row = o >> 7, c16 = (o >> 4) & 7;
          gload_lds16(Kh + hbase + (size_t)(s0n + row)*64 + (c16 ^ (row & 7))*8,
                      (char*)Kl[cur] + (jb + is)*1024);
        }
      } else {
        #pragma unroll
        for (int is = 0; is < 4; ++is) {
          int o = (jb + is)*1024 + lane*16;
          int row = o >> 7, c16 = (o >> 4) & 7;
          gload_lds16(Vt + hbase + (size_t)row*2048 + s0n + (c16 ^ (row & 7))*8,
                      (char*)Vl[cur] + (jb + is)*1024);
        }
      }
    }
    mcur = mnxt;
  }

  if (NS == 1) {
    const bool dead = (lrow == 0.f);
    const float rl = dead ? 0.f : 1.f / lrow;
    #pragma unroll
    for (int subd = 0; subd < 2; ++subd) {
      #pragma unroll
      for (int m = 0; m < 4; ++m) {
        const int d0 = subd*32 + hi*4 + m*8;
        float v0 = (subd ? cacc1[m*4+0] : cacc0[m*4+0]) * rl;
        float v1 = (subd ? cacc1[m*4+1] : cacc0[m*4+1]) * rl;
        float v2 = (subd ? cacc1[m*4+2] : cacc0[m*4+2]) * rl;
        float v3 = (subd ? cacc1[m*4+3] : cacc0[m*4+3]) * rl;
        if (dead) {
          const float* vs = vsum + bh*64 + d0;
          v0 = vs[0] * (1.0f/2048.0f);
          v1 = vs[1] * (1.0f/2048.0f);
          v2 = vs[2] * (1.0f/2048.0f);
          v3 = vs[3] * (1.0f/2048.0f);
        }
        ushort4 o;
        o.x = f2bf(v0); o.y = f2bf(v1); o.z = f2bf(v2); o.w = f2bf(v3);
        *(ushort4*)(ctx2 + (size_t)(q*2 + b)*1024 + h*64 + d0) = o;
      }
    }
  } else {
    const int row = w*32 + l31;
    if (!hi) {
      float2 ml; ml.x = mrow; ml.y = lrow;
      *(float2*)(pml + (size_t)(bh*36 + pml_off(k, ch))*256 + row*2) = ml;
    }
    u16* pc;
    if (ch == 0) {
      pc = ctx2 + (size_t)(q*2 + b)*1024 + h*64;
    } else {
      const int slot = bh*24 + pctx_off(k, ch);
      pc = (slot < 512) ? (pctxA + (size_t)slot*8192)
                        : (pctxB + (size_t)(slot - 512)*8192);
      pc += (size_t)row*64;
    }
    #pragma unroll
    for (int subd = 0; subd < 2; ++subd) {
      #pragma unroll
      for (int m = 0; m < 4; ++m) {
        const int d0 = subd*32 + hi*4 + m*8;
        const f32x16& cc = subd ? cacc1 : cacc0;
        ushort4 o;
        o.x = f2bf(cc[m*4+0]); o.y = f2bf(cc[m*4+1]);
        o.z = f2bf(cc[m*4+2]); o.w = f2bf(cc[m*4+3]);
        *(ushort4*)(pc + d0) = o;
      }
    }
  }
}

// ---------------- combine partials (2-4 way) ----------------
__global__ __launch_bounds__(256) void combine_kernel(
    const u16* __restrict__ pctxA, const u16* __restrict__ pctxB,
    const float* __restrict__ pml, const float* __restrict__ vsum,
    u16* __restrict__ ctx2)
{
  const int k = 4 + blockIdx.x;
  const int bh = blockIdx.y;
  const int NS = (k >> 2) + 1;            // 2,3,4
  const int b = bh >> 4, h = bh & 15;
  const int tid = threadIdx.x;
  const int row = tid >> 1, dh = (tid & 1) * 32;
  const int q = k*128 + row;

  const float* mlb = pml + (size_t)(bh*36 + pml_off(k, 0))*256 + row*2;
  float m0v = mlb[0],        l0v = mlb[1];
  float m1v = mlb[256+0],    l1v = mlb[256+1];
  float m2v = NEGINF, l2v = 0.f, m3v = NEGINF, l3v = 0.f;
  if (NS > 2) { m2v = mlb[512+0];  l2v = mlb[512+1]; }
  if (NS > 3) { m3v = mlb[768+0];  l3v = mlb[768+1]; }
  float ms = fmaxf(fmaxf(m0v, m1v), fmaxf(m2v, m3v));
  bool dead = (ms < -1e30f);
  const float w0 = dead ? 0.f : EXP2F(m0v - ms);
  const float w1 = dead ? 0.f : EXP2F(m1v - ms);
  const float w2 = (dead || NS <= 2) ? 0.f : EXP2F(m2v - ms);
  const float w3 = (dead || NS <= 3) ? 0.f : EXP2F(m3v - ms);
  const float lt = w0*l0v + w1*l1v + w2*l2v + w3*l3v;
  dead = dead || (lt == 0.f);
  const float rl = dead ? 0.f : 1.f / lt;

  u16* dst = ctx2 + (size_t)(q*2 + b)*1024 + h*64 + dh;
  const u16* pc1; const u16* pc2 = nullptr; const u16* pc3 = nullptr;
  {
    const int s1 = bh*24 + pctx_off(k, 1);
    pc1 = ((s1 < 512) ? (pctxA + (size_t)s1*8192) : (pctxB + (size_t)(s1-512)*8192))
          + (size_t)row*64 + dh;
    if (NS > 2) {
      const int s2 = bh*24 + pctx_off(k, 2);
      pc2 = ((s2 < 512) ? (pctxA + (size_t)s2*8192) : (pctxB + (size_t)(s2-512)*8192))
            + (size_t)row*64 + dh;
    }
    if (NS > 3) {
      const int s3 = bh*24 + pctx_off(k, 3);
      pc3 = ((s3 < 512) ? (pctxA + (size_t)s3*8192) : (pctxB + (size_t)(s3-512)*8192))
            + (size_t)row*64 + dh;
    }
  }
  #pragma unroll
  for (int g2 = 0; g2 < 4; ++g2) {
    bf16x8 a0 = *(const bf16x8*)(dst + g2*8);
    bf16x8 a1 = *(const bf16x8*)(pc1 + g2*8);
    bf16x8 o;
    #pragma unroll
    for (int j = 0; j < 8; ++j) {
      float v = w0*bf2f((u16)a0[j]) + w1*bf2f((u16)a1[j]);
      if (NS > 2) v += w2*bf2f((u16)((const u16*)pc2)[g2*8 + j]);
      if (NS > 3) v += w3*bf2f((u16)((const u16*)pc3)[g2*8 + j]);
      v *= rl;
      if (dead) v = vsum[bh*64 + dh + g2*8 + j] * (1.0f/2048.0f);
      o[j] = (short)f2bf(v);
    }
    *(bf16x8*)(dst + g2*8) = o;
  }
}

extern "C" void kernel_launch(void* const* d_in, const int* in_sizes, int n_in,
                              void* d_out, int out_size, void* d_ws, size_t ws_size,
                              hipStream_t stream) {
  const float* query = (const float*)d_in[0];
  const int*   kpm   = (const int*)d_in[1];
  const float* Wq = (const float*)d_in[3];
  const float* bq = (const float*)d_in[4];
  const float* Wk = (const float*)d_in[5];
  const float* bk = (const float*)d_in[6];
  const float* Wv = (const float*)d_in[7];
  const float* bv = (const float*)d_in[8];
  const float* Wo = (const float*)d_in[9];
  const float* bo = (const float*)d_in[10];

  char* ws = (char*)d_ws;
  u16*   qbf     = (u16*)(ws);               // [0,8M): query bf16 (dead after gemm_qkv)
  u16*   Vt      = (u16*)(ws);               // [0,8M): V^T (aliases qbf, written after)
  u16*   wbf     = (u16*)(ws + 8388608);     // [8M,16M): weights bf16
  u16*   pctxB   = (u16*)(ws + 8388608);     // [8M,12M): partials (dead Wq/Wk after qkv)
  u16*   qkvh    = (u16*)(ws + 16777216);    // [16M,40M): Q,K,V head-major
  u16*   pctxA   = (u16*)(ws + 33554432);    // [32M,40M): partials (dead V-orig)
  u16*   ctx2    = (u16*)(ws + 41943040);    // [40M,48M): attn output [T*B][E]
  float* vsum    = (float*)(ws + 50331648);  // [48M, +8K)
  float* pml     = (float*)(ws + 50339840);  // [48M+8K, +1.125M)
  u64*   kpmbits = (u64*)(ws + 51650560);    // 64 x u64

  cvt5_kernel<<<dim3(8193), 256, 0, stream>>>(query, Wq, Wk, Wv, Wo, kpm,
                                              qbf, wbf, kpmbits);

  hipMemsetAsync(vsum, 0, 2048 * sizeof(float), stream);

  gemm_qkv<<<dim3(32, 24), 512, 0, stream>>>(qbf, wbf, bq, bk, bv, qkvh);
  vtrans_kernel<<<dim3(1024), 256, 0, stream>>>(qkvh + 2*4194304, Vt, vsum);
  flash_attn<<<dim3(1280), 256, 0, stream>>>(qkvh, qkvh + 1*4194304,
                                             Vt, kpmbits, vsum, ctx2,
                                             pctxA, pctxB, pml);
  combine_kernel<<<dim3(12, 32), 256, 0, stream>>>(pctxA, pctxB, pml, vsum, ctx2);
  gemm_out<<<dim3(32, 8), 512, 0, stream>>>(ctx2, wbf + 3*1048576, bo, (float*)d_out);
}

// Round 13
// 138.864 us; speedup vs baseline: 1.0362x; 1.0362x over previous
//
#include <hip/hip_runtime.h>
#include <hip/hip_bf16.h>
#include <stdint.h>

typedef unsigned short u16;
typedef uint32_t u32;
typedef unsigned long long u64;
typedef __attribute__((ext_vector_type(8))) short bf16x8;
typedef __attribute__((ext_vector_type(4))) float f32x4;
typedef __attribute__((ext_vector_type(16))) float f32x16;
typedef __attribute__((ext_vector_type(2))) unsigned int u32x2;
typedef __attribute__((ext_vector_type(4))) u32 u32x4;

#define T_SEQ 2048

__device__ __forceinline__ float bf2f(u16 u) {
  union { u32 i; float f; } v; v.i = ((u32)u) << 16; return v.f;
}
__device__ __forceinline__ u16 f2bf(float f) {
  union { float f; u32 i; } v; v.f = f;
  u32 u = v.i;
  return (u16)((u + 0x7fffu + ((u >> 16) & 1u)) >> 16);
}

#if __has_builtin(__builtin_amdgcn_exp2f)
#define EXP2F(x) __builtin_amdgcn_exp2f(x)
#else
#define EXP2F(x) exp2f(x)
#endif

__device__ __forceinline__ u32 permpack(float lo, float hi) {
#if __has_builtin(__builtin_amdgcn_perm)
  return __builtin_amdgcn_perm(__float_as_uint(hi), __float_as_uint(lo), 0x07060302u);
#else
  return (__float_as_uint(hi) & 0xFFFF0000u) | (__float_as_uint(lo) >> 16);
#endif
}

__device__ __forceinline__ void plswap(u32& a, u32& b) {
#if __has_builtin(__builtin_amdgcn_permlane32_swap)
  u32x2 r = __builtin_amdgcn_permlane32_swap(a, b, false, false);
  a = r[0]; b = r[1];
#else
  u32 ra = __shfl_xor(a, 32, 64), rb = __shfl_xor(b, 32, 64);
  const bool hi_ = (threadIdx.x & 32) != 0;
  u32 na = hi_ ? rb : a;
  u32 nb = hi_ ? b : ra;
  a = na; b = nb;
#endif
}
__device__ __forceinline__ float othhalf(float x, bool ishi) {
  u32 a = __float_as_uint(x), b = a;
  plswap(a, b);
  return __uint_as_float(ishi ? a : b);
}

__device__ __forceinline__ void gload_lds16(const void* g, void* l) {
  __builtin_amdgcn_global_load_lds(
      (const __attribute__((address_space(1))) void*)g,
      (__attribute__((address_space(3))) void*)l, 16, 0, 0);
}

// ---- fp32 -> bf16 convert (query + 4 weights) + kpm bit-pack, one dispatch --
__global__ __launch_bounds__(256) void cvt5_kernel(
    const float* __restrict__ qsrc, const float* __restrict__ w0,
    const float* __restrict__ w1, const float* __restrict__ w2,
    const float* __restrict__ w3, const int* __restrict__ kpm,
    u16* __restrict__ qbf, u16* __restrict__ wbf, u64* __restrict__ kpmbits) {
  const int bx = blockIdx.x;
  if (bx == 8192) {
    const int wv = threadIdx.x >> 6, lane = threadIdx.x & 63;
    for (int pair = wv; pair < 64; pair += 4) {
      int v = kpm[pair*64 + lane];
      u64 m = __ballot(v != 0);
      if (lane == 0) kpmbits[pair] = m;
    }
    return;
  }
  const float* src; u16* dst; int i;
  if (bx < 4096) {
    src = qsrc; dst = qbf; i = (bx*256 + threadIdx.x)*4;
  } else {
    int t = bx - 4096;
    int z = t >> 10;
    src = (z == 0) ? w0 : (z == 1) ? w1 : (z == 2) ? w2 : w3;
    dst = wbf + (size_t)z * 1048576;
    i = ((t & 1023)*256 + threadIdx.x)*4;
  }
  const float4 v = *(const float4*)(src + i);
  ushort4 o;
  o.x = f2bf(v.x); o.y = f2bf(v.y); o.z = f2bf(v.z); o.w = f2bf(v.w);
  *(ushort4*)(dst + i) = o;
}

// ------- GEMM core: C[128x128] += A[128xK] * B[128xK]^T, K=1024, 8 waves ---
__device__ __forceinline__ void gemm_core_128x128(
    f32x4 acc[2][4], const u16* __restrict__ A, const u16* __restrict__ Bw,
    int bm, int bn, u16* As, u16* Bs)
{
  const int tid = threadIdx.x;
  const int w = tid >> 6, lane = tid & 63, g = lane >> 4, c = lane & 15;
  const int wr = (w & 3) * 32, wc = (w >> 2) * 64;
  for (int k0 = 0; k0 < 1024; k0 += 64) {
    __syncthreads();
    #pragma unroll
    for (int is = 0; is < 2; ++is) {
      int o = (is*8 + w)*1024 + lane*16;
      int row = o >> 7, c16 = (o >> 4) & 7;
      gload_lds16(A + (size_t)(bm*128 + row)*1024 + k0 + (c16 ^ (row & 7))*8,
                  (char*)As + (is*8 + w)*1024);
    }
    #pragma unroll
    for (int is = 0; is < 2; ++is) {
      int o = (is*8 + w)*1024 + lane*16;
      int row = o >> 7, c16 = (o >> 4) & 7;
      gload_lds16(Bw + (size_t)(bn*128 + row)*1024 + k0 + (c16 ^ (row & 7))*8,
                  (char*)Bs + (is*8 + w)*1024);
    }
    __syncthreads();
    bf16x8 af[2][2], bfr[4][2];
    #pragma unroll
    for (int mf = 0; mf < 2; ++mf)
      #pragma unroll
      for (int kc = 0; kc < 2; ++kc) {
        int row = wr + mf*16 + c;
        int colb = kc*64 + g*16;
        af[mf][kc] = *(const bf16x8*)((const char*)As + row*128 + (colb ^ ((row & 7) << 4)));
      }
    #pragma unroll
    for (int nf = 0; nf < 4; ++nf)
      #pragma unroll
      for (int kc = 0; kc < 2; ++kc) {
        int row = wc + nf*16 + c;
        int colb = kc*64 + g*16;
        bfr[nf][kc] = *(const bf16x8*)((const char*)Bs + row*128 + (colb ^ ((row & 7) << 4)));
      }
    #pragma unroll
    for (int mf = 0; mf < 2; ++mf)
      #pragma unroll
      for (int nf = 0; nf < 4; ++nf)
        #pragma unroll
        for (int kc = 0; kc < 2; ++kc)
          acc[mf][nf] = __builtin_amdgcn_mfma_f32_16x16x32_bf16(
              af[mf][kc], bfr[nf][kc], acc[mf][nf], 0, 0, 0);
  }
}

// ---------------- QKV projection: ONE dispatch over concat [3072][1024] ----
__global__ __launch_bounds__(512, 2) void gemm_qkv(
    const u16* __restrict__ Abf, const u16* __restrict__ Wbf,
    const float* __restrict__ bq, const float* __restrict__ bk,
    const float* __restrict__ bv, u16* __restrict__ qkvh)
{
  __shared__ __align__(16) u16 As[128*64];
  __shared__ __align__(16) u16 Bs[128*64];
  f32x4 acc[2][4];
  #pragma unroll
  for (int mf = 0; mf < 2; ++mf)
    #pragma unroll
    for (int nf = 0; nf < 4; ++nf) acc[mf][nf] = (f32x4){0.f,0.f,0.f,0.f};
  const int bm = blockIdx.x;
  gemm_core_128x128(acc, Abf, Wbf, bm, blockIdx.y, As, Bs);
  const int tid = threadIdx.x, w = tid >> 6, lane = tid & 63, g = lane >> 4, c = lane & 15;
  const int wr = (w & 3) * 32, wc = (w >> 2) * 64;
  #pragma unroll
  for (int mf = 0; mf < 2; ++mf)
    #pragma unroll
    for (int nf = 0; nf < 4; ++nf) {
      int col = blockIdx.y*128 + wc + nf*16 + c;      // 0..3071
      int z = col >> 10, colz = col & 1023;
      const float* bias = (z == 0) ? bq : (z == 1) ? bk : bv;
      float bcol = bias[colz];
      float scl = (z == 0) ? 0.18033688011112043f : 1.0f;  // 0.125 * log2(e)
      int h = colz >> 6, d = colz & 63;
      u16* dst = qkvh + (size_t)z * 4194304;
      #pragma unroll
      for (int r = 0; r < 4; ++r) {
        int row = bm*128 + wr + mf*16 + g*4 + r;
        int t = row >> 1, bb = row & 1;
        float v = (acc[mf][nf][r] + bcol) * scl;
        dst[(size_t)(bb*16 + h)*131072 + (size_t)t*64 + d] = f2bf(v);
      }
    }
}

// ---------------- output projection (128x128 tile, 512 thr) ----------------
__global__ __launch_bounds__(512, 2) void gemm_out(
    const u16* __restrict__ ctx2, const u16* __restrict__ Wobf,
    const float* __restrict__ bo, float* __restrict__ out)
{
  __shared__ __align__(16) u16 As[128*64];
  __shared__ __align__(16) u16 Bs[128*64];
  f32x4 acc[2][4];
  #pragma unroll
  for (int mf = 0; mf < 2; ++mf)
    #pragma unroll
    for (int nf = 0; nf < 4; ++nf) acc[mf][nf] = (f32x4){0.f,0.f,0.f,0.f};
  const int bm = blockIdx.x;
  gemm_core_128x128(acc, ctx2, Wobf, bm, blockIdx.y, As, Bs);
  const int tid = threadIdx.x, w = tid >> 6, lane = tid & 63, g = lane >> 4, c = lane & 15;
  const int wr = (w & 3) * 32, wc = (w >> 2) * 64;
  #pragma unroll
  for (int mf = 0; mf < 2; ++mf)
    #pragma unroll
    for (int nf = 0; nf < 4; ++nf) {
      int col = blockIdx.y*128 + wc + nf*16 + c;
      float bcol = bo[col];
      #pragma unroll
      for (int r = 0; r < 4; ++r) {
        int row = bm*128 + wr + mf*16 + g*4 + r;
        out[(size_t)row*1024 + col] = acc[mf][nf][r] + bcol;
      }
    }
}

// ---------------- V transpose + column sums ----------------
__global__ __launch_bounds__(256) void vtrans_kernel(const u16* __restrict__ Vh,
                                                     u16* __restrict__ Vt,
                                                     float* __restrict__ vs) {
  __shared__ u16 tile[64][72];
  const int bh = blockIdx.x >> 5, tc = blockIdx.x & 31;
  const int t0 = tc * 64;
  const int tid = threadIdx.x;
  {
    const int tl = tid >> 2, d0 = (tid & 3) * 16;
    const u16* src = Vh + (size_t)bh*131072 + (size_t)(t0 + tl)*64 + d0;
    bf16x8 a = *(const bf16x8*)src;
    bf16x8 b2 = *(const bf16x8*)(src + 8);
    #pragma unroll
    for (int j = 0; j < 8; ++j) {
      tile[d0 + j][tl] = (u16)a[j];
      tile[d0 + 8 + j][tl] = (u16)b2[j];
    }
  }
  __syncthreads();
  {
    const int d = tid >> 2, tq = (tid & 3) * 16;
    bf16x8 o0, o1;
    float s = 0.f;
    #pragma unroll
    for (int j = 0; j < 8; ++j) {
      u16 x0 = tile[d][tq + j], x1 = tile[d][tq + 8 + j];
      o0[j] = (short)x0; o1[j] = (short)x1;
      s += bf2f(x0) + bf2f(x1);
    }
    u16* dst = Vt + (size_t)bh*131072 + (size_t)d*2048 + t0 + tq;
    *(bf16x8*)dst = o0;
    *(bf16x8*)(dst + 8) = o1;
    s += __shfl_xor(s, 1, 64);
    s += __shfl_xor(s, 2, 64);
    if ((tid & 3) == 0) atomicAdd(&vs[bh*64 + d], s);
  }
}

// ---------------- flash attention: 4 blocks/CU, counted-vmcnt --------------
// grid 1024 = 8 XCD x 4 bh x 32 chunks. VGPR=92 -> HW allows exactly 4 waves/
// SIMD -> 4 blocks/CU resident (R11/R12's 5/CU plan left a straggler; this is
// the fix). Chunking: k<=4 single, k5-10 halves, k11-15 thirds; max chunk 11
// iters; quartets at cidx stride 8 (same-XCD round-robin -> same CU) sum 34,
// longest-first. Pipeline: T4 counted vmcnt(4), 2-deep, as R12.
#define ZERO16 (f32x16){0.f,0.f,0.f,0.f,0.f,0.f,0.f,0.f,0.f,0.f,0.f,0.f,0.f,0.f,0.f,0.f}
#define NEGINF (-__builtin_inff())

// CTBL[cidx] = (k<<2)|ch; quartet q at cidx {q, q+8, q+16, q+24}
__device__ const unsigned char CTBL[32] = {
  40, 61, 36, 56, 58, 54, 52, 49,
  41, 62, 37, 57, 60, 32, 53, 50,
  16, 12, 28, 29, 44, 45, 33, 46,
   0,  4,  8, 20, 21, 24, 25, 48 };

// ch>=1 partial-ctx slots: 16 per bh (k5-10: 1 each; k11-15: 2 each)
__device__ __forceinline__ int pctx_off(int k, int ch) {
  if (k < 11) return (k - 5);
  return 6 + (k - 11)*2 + (ch - 1);
}
// pml slots: 27 per bh (k5-10: 2 each; k11-15: 3 each)
__device__ __forceinline__ int pml_off(int k, int ch) {
  if (k < 11) return (k - 5)*2 + ch;
  return 12 + (k - 11)*3 + ch;
}

__global__ __launch_bounds__(256, 2) void flash_attn(
    const u16* __restrict__ Qh, const u16* __restrict__ Kh,
    const u16* __restrict__ Vt, const u64* __restrict__ kpmbits,
    const float* __restrict__ vsum, u16* __restrict__ ctx2,
    u16* __restrict__ pctxA, float* __restrict__ pml)
{
  __shared__ __align__(16) u16 Kl[2][4096];
  __shared__ __align__(16) u16 Vl[2][4096];

  const int tid = threadIdx.x;
  const int w = tid >> 6, lane = tid & 63;
  const int l31 = lane & 31, hi = lane >> 5;

  const int id = blockIdx.x;
  const int xcd = id & 7, rest = id >> 3;
  const int bh = xcd * 4 + (rest & 3);
  const int cidx = rest >> 2;            // 0..31
  const int v_tbl = CTBL[cidx];
  const int k = v_tbl >> 2, ch = v_tbl & 3;
  const int NS = (k <= 4) ? 1 : (k <= 10) ? 2 : 3;
  const int nt = 2*k + 2;
  const int lo = (nt * ch) / NS, hicap = (nt * (ch + 1)) / NS;

  const int b = bh >> 4, h = bh & 15;
  const size_t hbase = (size_t)bh * 131072;
  const int q = 128*k + 32*w + l31;
  const int myNt = 2*k + 1 + (w >> 1);

  bf16x8 qfrag[4];
  #pragma unroll
  for (int kt = 0; kt < 4; ++kt)
    qfrag[kt] = *(const bf16x8*)(Qh + hbase + (size_t)q*64 + kt*16 + hi*8);

  const int jb = (w & 1) * 4;

  u64 mcur = kpmbits[(b << 5) + lo];
  {
    const int s0t = lo * 64;
    if (w < 2) {
      #pragma unroll
      for (int is = 0; is < 4; ++is) {
        int o = (jb + is)*1024 + lane*16;
        int row = o >> 7, c16 = (o >> 4) & 7;
        gload_lds16(Kh + hbase + (size_t)(s0t + row)*64 + (c16 ^ (row & 7))*8,
                    (char*)Kl[0] + (jb + is)*1024);
      }
    } else {
      #pragma unroll
      for (int is = 0; is < 4; ++is) {
        int o = (jb + is)*1024 + lane*16;
        int row = o >> 7, c16 = (o >> 4) & 7;
        gload_lds16(Vt + hbase + (size_t)row*2048 + s0t + (c16 ^ (row & 7))*8,
                    (char*)Vl[0] + (jb + is)*1024);
      }
    }
  }
  if (lo + 1 < hicap) {
    const int s0t = (lo + 1) * 64;
    if (w < 2) {
      #pragma unroll
      for (int is = 0; is < 4; ++is) {
        int o = (jb + is)*1024 + lane*16;
        int row = o >> 7, c16 = (o >> 4) & 7;
        gload_lds16(Kh + hbase + (size_t)(s0t + row)*64 + (c16 ^ (row & 7))*8,
                    (char*)Kl[1] + (jb + is)*1024);
      }
    } else {
      #pragma unroll
      for (int is = 0; is < 4; ++is) {
        int o = (jb + is)*1024 + lane*16;
        int row = o >> 7, c16 = (o >> 4) & 7;
        gload_lds16(Vt + hbase + (size_t)row*2048 + s0t + (c16 ^ (row & 7))*8,
                    (char*)Vl[1] + (jb + is)*1024);
      }
    }
  }

  float mrow = NEGINF, lrow = 0.f;
  f32x16 cacc0 = ZERO16, cacc1 = ZERO16;

  for (int t = lo; t < hicap; ++t) {
    const int cur = (t - lo) & 1;
    const int s0 = t * 64;
    const bool haveNext = (t + 1 < hicap);
    const bool diag = (t >= myNt - 1);

    if (haveNext) asm volatile("s_waitcnt vmcnt(4)" ::: "memory");
    else          asm volatile("s_waitcnt vmcnt(0)" ::: "memory");
    u64 mnxt = haveNext ? kpmbits[(b << 5) + t + 1] : 0;
    __builtin_amdgcn_s_barrier();

    u32 kill0 = 0, kill1 = 0;
    {
      const u32 m0 = (u32)mcur, m1 = (u32)(mcur >> 32);
      const u64 m4 = mcur >> 4;
      const u32 m4l = (u32)m4, m4h = (u32)(m4 >> 32);
      const u32 w0m = hi ? m4l : m0;
      const u32 w1m = hi ? m4h : m1;
      const int lim = q - s0 - 4*hi;
      #pragma unroll
      for (int m = 0; m < 4; ++m) {
        u32 nib0 = (w0m >> (m*8)) & 15u;
        u32 nib1 = (w1m >> (m*8)) & 15u;
        if (diag) {
          int t0c = lim - m*8;       int c0 = min(max(t0c + 1, 0), 4);
          int t1c = lim - 32 - m*8;  int c1 = min(max(t1c + 1, 0), 4);
          nib0 |= (0xFu << c0) & 0xFu;
          nib1 |= (0xFu << c1) & 0xFu;
        }
        kill0 |= nib0 << (m*4);
        kill1 |= nib1 << (m*4);
      }
    }
    f32x16 st0, st1;
    #pragma unroll
    for (int i = 0; i < 16; ++i) {
      st0[i] = ((kill0 >> i) & 1u) ? NEGINF : 0.f;
      st1[i] = ((kill1 >> i) & 1u) ? NEGINF : 0.f;
    }

    bf16x8 kreg[2][4], vf[2][4];
    #pragma unroll
    for (int sub = 0; sub < 2; ++sub)
      #pragma unroll
      for (int kt = 0; kt < 4; ++kt) {
        int row = sub*32 + l31;
        int colb = kt*32 + hi*16;
        kreg[sub][kt] = *(const bf16x8*)((const char*)Kl[cur] + row*128 + (colb ^ ((row & 7) << 4)));
        vf[sub][kt]   = *(const bf16x8*)((const char*)Vl[cur] + row*128 + (colb ^ ((row & 7) << 4)));
      }

    __builtin_amdgcn_s_setprio(1);
    #pragma unroll
    for (int kt = 0; kt < 4; ++kt) {
      st0 = __builtin_amdgcn_mfma_f32_32x32x16_bf16(kreg[0][kt], qfrag[kt], st0, 0, 0, 0);
      st1 = __builtin_amdgcn_mfma_f32_32x32x16_bf16(kreg[1][kt], qfrag[kt], st1, 0, 0, 0);
    }
    __builtin_amdgcn_s_setprio(0);

    {
      float t8[8];
      #pragma unroll
      for (int i = 0; i < 8; ++i)
        t8[i] = fmaxf(fmaxf(st0[i], st0[i+8]), fmaxf(st1[i], st1[i+8]));
      float t4a = fmaxf(t8[0], t8[4]), t4b = fmaxf(t8[1], t8[5]);
      float t4c = fmaxf(t8[2], t8[6]), t4d = fmaxf(t8[3], t8[7]);
      float rm = fmaxf(fmaxf(t4a, t4b), fmaxf(t4c, t4d));
      rm = fmaxf(rm, othhalf(rm, hi != 0));

      const bool need = (rm > mrow + 8.f) || (mrow < -1e30f);
      if (__any(need)) {
        const float mn = fmaxf(mrow, rm);
        const float sc = (mn < -1e30f) ? 1.f : EXP2F(mrow - mn);
        mrow = mn;
        lrow *= sc;
        #pragma unroll
        for (int i = 0; i < 16; ++i) { cacc0[i] *= sc; cacc1[i] *= sc; }
      }
      const bool dead = (mrow < -1e30f);
      float a0 = 0.f, a1 = 0.f, a2 = 0.f, a3 = 0.f;
      #pragma unroll
      for (int i = 0; i < 16; i += 4) {
        float p0 = dead ? 0.f : EXP2F(st0[i+0] - mrow); st0[i+0] = p0; a0 += p0;
        float p1 = dead ? 0.f : EXP2F(st0[i+1] - mrow); st0[i+1] = p1; a1 += p1;
        float p2 = dead ? 0.f : EXP2F(st0[i+2] - mrow); st0[i+2] = p2; a2 += p2;
        float p3 = dead ? 0.f : EXP2F(st0[i+3] - mrow); st0[i+3] = p3; a3 += p3;
      }
      #pragma unroll
      for (int i = 0; i < 16; i += 4) {
        float p0 = dead ? 0.f : EXP2F(st1[i+0] - mrow); st1[i+0] = p0; a0 += p0;
        float p1 = dead ? 0.f : EXP2F(st1[i+1] - mrow); st1[i+1] = p1; a1 += p1;
        float p2 = dead ? 0.f : EXP2F(st1[i+2] - mrow); st1[i+2] = p2; a2 += p2;
        float p3 = dead ? 0.f : EXP2F(st1[i+3] - mrow); st1[i+3] = p3; a3 += p3;
      }
      float ps = (a0 + a1) + (a2 + a3);
      ps += othhalf(ps, hi != 0);
      lrow += ps;
    }

    u32 pk[8][2];
    #pragma unroll
    for (int m = 0; m < 4; ++m) {
      pk[m][0]   = permpack(st0[m*4+0], st0[m*4+1]);
      pk[m][1]   = permpack(st0[m*4+2], st0[m*4+3]);
      pk[4+m][0] = permpack(st1[m*4+0], st1[m*4+1]);
      pk[4+m][1] = permpack(st1[m*4+2], st1[m*4+3]);
    }
    bf16x8 pf[4];
    #pragma unroll
    for (int ks = 0; ks < 4; ++ks) {
      u32 w0p = pk[2*ks][0], w2p = pk[2*ks+1][0];
      u32 w1p = pk[2*ks][1], w3p = pk[2*ks+1][1];
      plswap(w0p, w2p);
      plswap(w1p, w3p);
      u32x4 wv = {w0p, w1p, w2p, w3p};
      pf[ks] = __builtin_bit_cast(bf16x8, wv);
    }

    __builtin_amdgcn_s_setprio(1);
    #pragma unroll
    for (int ks = 0; ks < 4; ++ks)
      cacc0 = __builtin_amdgcn_mfma_f32_32x32x16_bf16(vf[0][ks], pf[ks], cacc0, 0, 0, 0);
    #pragma unroll
    for (int ks = 0; ks < 4; ++ks)
      cacc1 = __builtin_amdgcn_mfma_f32_32x32x16_bf16(vf[1][ks], pf[ks], cacc1, 0, 0, 0);
    __builtin_amdgcn_s_setprio(0);

    __builtin_amdgcn_s_barrier();
    if (t + 2 < hicap) {
      const int s0n = (t + 2) * 64;
      if (w < 2) {
        #pragma unroll
        for (int is = 0; is < 4; ++is) {
          int o = (jb + is)*1024 + lane*16;
          int row = o >> 7, c16 = (o >> 4) & 7;
          gload_lds16(Kh + hbase + (size_t)(s0n + row)*64 + (c16 ^ (row & 7))*8,
                      (char*)Kl[cur] + (jb + is)*1024);
        }
      } else {
        #pragma unroll
        for (int is = 0; is < 4; ++is) {
          int o = (jb + is)*1024 + lane*16;
          int row = o >> 7, c16 = (o >> 4) & 7;
          gload_lds16(Vt + hbase + (size_t)row*2048 + s0n + (c16 ^ (row & 7))*8,
                      (char*)Vl[cur] + (jb + is)*1024);
        }
      }
    }
    mcur = mnxt;
  }

  if (NS == 1) {
    const bool dead = (lrow == 0.f);
    const float rl = dead ? 0.f : 1.f / lrow;
    #pragma unroll
    for (int subd = 0; subd < 2; ++subd) {
      #pragma unroll
      for (int m = 0; m < 4; ++m) {
        const int d0 = subd*32 + hi*4 + m*8;
        float v0 = (subd ? cacc1[m*4+0] : cacc0[m*4+0]) * rl;
        float v1 = (subd ? cacc1[m*4+1] : cacc0[m*4+1]) * rl;
        float v2 = (subd ? cacc1[m*4+2] : cacc0[m*4+2]) * rl;
        float v3 = (subd ? cacc1[m*4+3] : cacc0[m*4+3]) * rl;
        if (dead) {
          const float* vs = vsum + bh*64 + d0;
          v0 = vs[0] * (1.0f/2048.0f);
          v1 = vs[1] * (1.0f/2048.0f);
          v2 = vs[2] * (1.0f/2048.0f);
          v3 = vs[3] * (1.0f/2048.0f);
        }
        ushort4 o;
        o.x = f2bf(v0); o.y = f2bf(v1); o.z = f2bf(v2); o.w = f2bf(v3);
        *(ushort4*)(ctx2 + (size_t)(q*2 + b)*1024 + h*64 + d0) = o;
      }
    }
  } else {
    const int row = w*32 + l31;
    if (!hi) {
      float2 ml; ml.x = mrow; ml.y = lrow;
      *(float2*)(pml + (size_t)(bh*27 + pml_off(k, ch))*256 + row*2) = ml;
    }
    u16* pc;
    if (ch == 0) {
      pc = ctx2 + (size_t)(q*2 + b)*1024 + h*64;
    } else {
      const int slot = bh*16 + pctx_off(k, ch);
      pc = pctxA + (size_t)slot*8192 + (size_t)row*64;
    }
    #pragma unroll
    for (int subd = 0; subd < 2; ++subd) {
      #pragma unroll
      for (int m = 0; m < 4; ++m) {
        const int d0 = subd*32 + hi*4 + m*8;
        const f32x16& cc = subd ? cacc1 : cacc0;
        ushort4 o;
        o.x = f2bf(cc[m*4+0]); o.y = f2bf(cc[m*4+1]);
        o.z = f2bf(cc[m*4+2]); o.w = f2bf(cc[m*4+3]);
        *(ushort4*)(pc + d0) = o;
      }
    }
  }
}

// ---------------- combine partials (2-3 way) ----------------
// grid (11, 32): k = 5+bx, bh = by. thread: row = tid>>1, dhalf.
__global__ __launch_bounds__(256) void combine_kernel(
    const u16* __restrict__ pctxA, const float* __restrict__ pml,
    const float* __restrict__ vsum, u16* __restrict__ ctx2)
{
  const int k = 5 + blockIdx.x;
  const int bh = blockIdx.y;
  const int NS = (k <= 10) ? 2 : 3;
  const int b = bh >> 4, h = bh & 15;
  const int tid = threadIdx.x;
  const int row = tid >> 1, dh = (tid & 1) * 32;
  const int q = k*128 + row;

  const float* mlb = pml + (size_t)(bh*27 + pml_off(k, 0))*256 + row*2;
  float m0v = mlb[0],     l0v = mlb[1];
  float m1v = mlb[256+0], l1v = mlb[256+1];
  float m2v = NEGINF, l2v = 0.f;
  if (NS > 2) { m2v = mlb[512+0]; l2v = mlb[512+1]; }
  float ms = fmaxf(fmaxf(m0v, m1v), m2v);
  bool dead = (ms < -1e30f);
  const float w0 = dead ? 0.f : EXP2F(m0v - ms);
  const float w1 = dead ? 0.f : EXP2F(m1v - ms);
  const float w2 = (dead || NS <= 2) ? 0.f : EXP2F(m2v - ms);
  const float lt = w0*l0v + w1*l1v + w2*l2v;
  dead = dead || (lt == 0.f);
  const float rl = dead ? 0.f : 1.f / lt;

  u16* dst = ctx2 + (size_t)(q*2 + b)*1024 + h*64 + dh;
  const u16* pc1 = pctxA + (size_t)(bh*16 + pctx_off(k, 1))*8192 + (size_t)row*64 + dh;
  const u16* pc2 = nullptr;
  if (NS > 2)
    pc2 = pctxA + (size_t)(bh*16 + pctx_off(k, 2))*8192 + (size_t)row*64 + dh;

  #pragma unroll
  for (int g2 = 0; g2 < 4; ++g2) {
    bf16x8 a0 = *(const bf16x8*)(dst + g2*8);
    bf16x8 a1 = *(const bf16x8*)(pc1 + g2*8);
    bf16x8 o;
    #pragma unroll
    for (int j = 0; j < 8; ++j) {
      float v = w0*bf2f((u16)a0[j]) + w1*bf2f((u16)a1[j]);
      if (NS > 2) v += w2*bf2f((u16)pc2[g2*8 + j]);
      v *= rl;
      if (dead) v = vsum[bh*64 + dh + g2*8 + j] * (1.0f/2048.0f);
      o[j] = (short)f2bf(v);
    }
    *(bf16x8*)(dst + g2*8) = o;
  }
}

extern "C" void kernel_launch(void* const* d_in, const int* in_sizes, int n_in,
                              void* d_out, int out_size, void* d_ws, size_t ws_size,
                              hipStream_t stream) {
  const float* query = (const float*)d_in[0];
  const int*   kpm   = (const int*)d_in[1];
  const float* Wq = (const float*)d_in[3];
  const float* bq = (const float*)d_in[4];
  const float* Wk = (const float*)d_in[5];
  const float* bk = (const float*)d_in[6];
  const float* Wv = (const float*)d_in[7];
  const float* bv = (const float*)d_in[8];
  const float* Wo = (const float*)d_in[9];
  const float* bo = (const float*)d_in[10];

  char* ws = (char*)d_ws;
  u16*   qbf     = (u16*)(ws);               // [0,8M): query bf16 (dead after gemm_qkv)
  u16*   Vt      = (u16*)(ws);               // [0,8M): V^T (aliases qbf, written after)
  u16*   wbf     = (u16*)(ws + 8388608);     // [8M,16M): weights bf16
  u16*   qkvh    = (u16*)(ws + 16777216);    // [16M,40M): Q,K,V head-major
  u16*   pctxA   = (u16*)(ws + 33554432);    // [32M,40M): partials (dead V-orig)
  u16*   ctx2    = (u16*)(ws + 41943040);    // [40M,48M): attn output [T*B][E]
  float* vsum    = (float*)(ws + 50331648);  // [48M, +8K)
  float* pml     = (float*)(ws + 50339840);  // [48M+8K, +0.9M)
  u64*   kpmbits = (u64*)(ws + 51650560);    // 64 x u64

  cvt5_kernel<<<dim3(8193), 256, 0, stream>>>(query, Wq, Wk, Wv, Wo, kpm,
                                              qbf, wbf, kpmbits);

  hipMemsetAsync(vsum, 0, 2048 * sizeof(float), stream);

  gemm_qkv<<<dim3(32, 24), 512, 0, stream>>>(qbf, wbf, bq, bk, bv, qkvh);
  vtrans_kernel<<<dim3(1024), 256, 0, stream>>>(qkvh + 2*4194304, Vt, vsum);
  flash_attn<<<dim3(1024), 256, 0, stream>>>(qkvh, qkvh + 1*4194304,
                                             Vt, kpmbits, vsum, ctx2,
                                             pctxA, pml);
  combine_kernel<<<dim3(11, 32), 256, 0, stream>>>(pctxA, pml, vsum, ctx2);
  gemm_out<<<dim3(32, 8), 512, 0, stream>>>(ctx2, wbf + 3*1048576, bo, (float*)d_out);
}